// Round 11
// baseline (218.505 us; speedup 1.0000x reference)
//
#include <hip/hip_runtime.h>
#include <hip/hip_bf16.h>

#define HID 64
#define REL 5
#define EPB 4096          // edges per partition block (16/thread * 256)
#define BKT 256           // nodes per sort bucket

typedef short bf16x8 __attribute__((ext_vector_type(8)));
typedef float f32x4 __attribute__((ext_vector_type(4)));

__device__ __forceinline__ float bf2f(unsigned short u) {
    return __uint_as_float(((unsigned)u) << 16);
}
__device__ __forceinline__ unsigned short f2bf(float f) {
    __hip_bfloat16 h = (__hip_bfloat16)f;   // RNE
    return *(unsigned short*)&h;
}
// Per-wave inline dtype detection (no separate kernel, no flags buffer).
__device__ __forceinline__ int det_f32(const unsigned short* __restrict__ wb) {
    int lane = threadIdx.x & 63;
    bool big = (lane < 32) ? (fabsf(bf2f(wb[2 * lane])) > 0.26f) : false;
    return (__ballot(big) != 0ull) ? 1 : 0;
}
__device__ __forceinline__ int det_i64(const int* __restrict__ ei) {
    int lane = threadIdx.x & 63;
    bool odd_nz = (ei[2 * lane + 1] != 0);
    return (__ballot(odd_nz) == 0ull) ? 1 : 0;
}
__device__ __forceinline__ void dec_edge(const int* __restrict__ ei, int i64,
                                         int E, int e, int& r, int& c) {
    if (i64) { r = ei[2 * e]; c = ei[2 * (E + e)]; }
    else     { r = ei[e];     c = ei[E + e]; }
}

// ---------------------------------------------------------------------------
// K_pack: weights -> per-lane MFMA B-fragment order, bf16.
// Bpk[mat][ks][nt][lane][j]; mat: 0=Win, 1..5=Wrel, 6=Wout.
// ---------------------------------------------------------------------------
__global__ void k_pack(const void* Win, const void* bin, const void* Wr,
                       const void* Wout, const void* bout,
                       unsigned short* __restrict__ Bpk,
                       float* __restrict__ binf, float* __restrict__ boutf) {
    int f = det_f32((const unsigned short*)bin);
    int gid = blockIdx.x * 256 + threadIdx.x;
    if (gid < 7 * 2 * 4 * 64) {
        int lane = gid & 63;
        int nt = (gid >> 6) & 3;
        int ks = (gid >> 8) & 1;
        int mat = gid >> 9;
        int q = lane >> 4, n = nt * 16 + (lane & 15);
#pragma unroll
        for (int j = 0; j < 8; j++) {
            int k = ks * 32 + q * 8 + j;
            int idx = k * 64 + n;
            float val;
            if (mat == 0)
                val = f ? ((const float*)Win)[idx] : bf2f(((const unsigned short*)Win)[idx]);
            else if (mat <= 5) {
                int ii = (mat - 1) * 4096 + idx;
                val = f ? ((const float*)Wr)[ii] : bf2f(((const unsigned short*)Wr)[ii]);
            } else
                val = f ? ((const float*)Wout)[idx] : bf2f(((const unsigned short*)Wout)[idx]);
            Bpk[(size_t)gid * 8 + j] = f2bf(val);
        }
    }
    if (gid < 64)
        binf[gid] = f ? ((const float*)bin)[gid] : bf2f(((const unsigned short*)bin)[gid]);
    else if (gid >= 64 && gid < 128) {
        int i = gid - 64;
        boutf[i] = f ? ((const float*)bout)[i] : bf2f(((const unsigned short*)bout)[i]);
    }
}

// ---------------------------------------------------------------------------
// P1a: per-block LDS histograms of r/BKT and c/BKT.
// ---------------------------------------------------------------------------
__global__ void k_p1a(const int* __restrict__ ei,
                      int* __restrict__ hist, int E, int NB, int nblk) {
    extern __shared__ int lh[];  // 2*NB
    int i64 = det_i64(ei);
    int tid = threadIdx.x, blk = blockIdx.x;
    for (int i = tid; i < 2 * NB; i += 256) lh[i] = 0;
    __syncthreads();
#pragma unroll
    for (int k = 0; k < EPB / 256; k++) {
        int e = blk * EPB + k * 256 + tid;
        if (e < E) {
            int r, c;
            dec_edge(ei, i64, E, e, r, c);
            atomicAdd(&lh[r >> 8], 1);
            atomicAdd(&lh[NB + (c >> 8)], 1);
        }
    }
    __syncthreads();
    int NBn = NB * nblk;
    for (int i = tid; i < NB; i += 256) {
        hist[i * nblk + blk] = lh[i];
        hist[NBn + i * nblk + blk] = lh[NB + i];
    }
}

// ---------------------------------------------------------------------------
// Scan (2 kernels)
// ---------------------------------------------------------------------------
__global__ void s_blk(const int* __restrict__ v, int* __restrict__ bsum, int M) {
    __shared__ int red[256];
    int t = threadIdx.x;
    int i0 = blockIdx.x * 1024 + t * 4;
    int s = 0;
#pragma unroll
    for (int j = 0; j < 4; j++) { int i = i0 + j; if (i < M) s += v[i]; }
    red[t] = s;
    __syncthreads();
    for (int d = 128; d > 0; d >>= 1) {
        if (t < d) red[t] += red[t + d];
        __syncthreads();
    }
    if (t == 0) bsum[blockIdx.x] = red[0];
}

__global__ void s_apply(int* __restrict__ v, const int* __restrict__ bsum,
                        int M, int nsb) {
    __shared__ int red[256];
    int t = threadIdx.x, bk = blockIdx.x;
    int acc = 0;
    for (int i = t; i < nsb; i += 256)
        if (i < bk) acc += bsum[i];
    red[t] = acc;
    __syncthreads();
    for (int d = 128; d > 0; d >>= 1) {
        if (t < d) red[t] += red[t + d];
        __syncthreads();
    }
    int base = red[0];
    __syncthreads();
    int i0 = bk * 1024 + t * 4;
    int x[4];
    int s = 0;
#pragma unroll
    for (int j = 0; j < 4; j++) {
        int i = i0 + j;
        x[j] = (i < M) ? v[i] : 0;
        s += x[j];
    }
    red[t] = s;
    __syncthreads();
    for (int d = 1; d < 256; d <<= 1) {
        int add = (t >= d) ? red[t - d] : 0;
        __syncthreads();
        red[t] += add;
        __syncthreads();
    }
    int run = base + red[t] - s;
#pragma unroll
    for (int j = 0; j < 4; j++) {
        int i = i0 + j;
        if (i < M) { int tmp = x[j]; v[i] = run; run += tmp; }
    }
}

// ---------------------------------------------------------------------------
// P1c: partition. rbuf[posR] = (r&255)<<20 | t<<17 | c ; cb8[posC] = c&255.
// ---------------------------------------------------------------------------
__global__ void k_p1c(const int* __restrict__ ei, const int* __restrict__ et,
                      const int* __restrict__ hist,
                      unsigned* __restrict__ rbuf, unsigned char* __restrict__ cb8,
                      int E, int NB, int nblk) {
    extern __shared__ int lh[];  // 2*NB rank counters
    int i64 = det_i64(ei);
    int tid = threadIdx.x, blk = blockIdx.x;
    for (int i = tid; i < 2 * NB; i += 256) lh[i] = 0;
    __syncthreads();
    int NBn = NB * nblk;
#pragma unroll
    for (int k = 0; k < EPB / 256; k++) {
        int e = blk * EPB + k * 256 + tid;
        if (e < E) {
            int r, c;
            dec_edge(ei, i64, E, e, r, c);
            int t = et[e];
            int binR = r >> 8;
            int posR = hist[binR * nblk + blk] + atomicAdd(&lh[binR], 1);
            rbuf[posR] = ((unsigned)(r & 255) << 20) | ((unsigned)t << 17) | (unsigned)c;
            int binC = c >> 8;
            int posC = hist[NBn + binC * nblk + blk] - E + atomicAdd(&lh[NB + binC], 1);
            cb8[posC] = (unsigned char)(c & 255);
        }
    }
}

// ---------------------------------------------------------------------------
// P2 (merged): blocks [0,NB) = r-side (off[] + final edata4);
//              blocks [NB,2NB) = c-side (dis[]).
// ---------------------------------------------------------------------------
__global__ void k_p2(const unsigned* __restrict__ rbuf, const unsigned char* __restrict__ cb8,
                     const int* __restrict__ hist,
                     int* __restrict__ off, unsigned* __restrict__ edata4,
                     float* __restrict__ dis, int E, int N, int NB, int nblk) {
    __shared__ int lcnt[BKT], excl[BKT], lcnt2[BKT];
    int tid = threadIdx.x;
    int bk = blockIdx.x;
    if (bk < NB) {
        int bstart = hist[bk * nblk];
        int bend = (bk + 1 < NB) ? hist[(bk + 1) * nblk] : E;
        lcnt[tid] = 0; lcnt2[tid] = 0;
        __syncthreads();
        for (int e = bstart + tid; e < bend; e += 256)
            atomicAdd(&lcnt[(rbuf[e] >> 20) & 255], 1);
        __syncthreads();
        int s = lcnt[tid];
        excl[tid] = s;
        __syncthreads();
        for (int d = 1; d < 256; d <<= 1) {
            int add = (tid >= d) ? excl[tid - d] : 0;
            __syncthreads();
            excl[tid] += add;
            __syncthreads();
        }
        int base = excl[tid] - s;
        excl[tid] = base;
        __syncthreads();
        int node = bk * BKT + tid;
        if (node < N) off[node] = bstart + base;
        if (bk == 0 && tid == 0) off[N] = E;
        for (int e = bstart + tid; e < bend; e += 256) {
            unsigned rec = rbuf[e];
            int rl = (rec >> 20) & 255;
            int t = (rec >> 17) & 7;
            int c = rec & 0x1FFFF;
            int pos = bstart + excl[rl] + atomicAdd(&lcnt2[rl], 1);
            edata4[pos] = (unsigned)c | ((unsigned)t << 20);
        }
    } else {
        int bk2 = bk - NB;
        int NBn = NB * nblk;
        int cstart = hist[NBn + bk2 * nblk] - E;
        int cend = (bk2 + 1 < NB) ? hist[NBn + (bk2 + 1) * nblk] - E : E;
        lcnt[tid] = 0;
        __syncthreads();
        for (int e = cstart + tid; e < cend; e += 256)
            atomicAdd(&lcnt[cb8[e]], 1);
        __syncthreads();
        int node = bk2 * BKT + tid;   // covers all Np
        int d = lcnt[tid];
        dis[node] = (d > 0) ? rsqrtf((float)d) : 0.f;   // padding nodes -> 0
    }
}

// ---------------------------------------------------------------------------
// K_xy (MFMA): x = A@Win + b ; Y[r] = bf16(x)@Wrel[r].
// Yi layout [5][Np] rows of 128 ushorts: 2*ch = y[ch], 2*ch+1 = (x*dis)[ch].
// ---------------------------------------------------------------------------
__device__ __forceinline__ bf16x8 load_a8(const void* A, int f, size_t base) {
    if (f) {
        const float* Af = (const float*)A + base;
        bf16x8 r;
#pragma unroll
        for (int j = 0; j < 8; j++) r[j] = (short)f2bf(Af[j]);
        return r;
    }
    return *(const bf16x8*)((const unsigned short*)A + base);
}

__global__ void __launch_bounds__(256)
k_xy(const void* __restrict__ A, const void* __restrict__ binp,
     const unsigned short* __restrict__ Bpk,
     const float* __restrict__ binf, const float* __restrict__ dis,
     unsigned short* __restrict__ Yi, int N, int Np) {
    __shared__ unsigned short Bs[6 * 2 * 4 * 64 * 8];  // 48 KB
    __shared__ unsigned short Xs[64 * 64];             // 8 KB  x (frag source)
    __shared__ unsigned short Xss[64 * 64];            // 8 KB  x*dis
    __shared__ unsigned short Ys[64 * 64];             // 8 KB  y staging
    __shared__ float bs[64];
    int f = det_f32((const unsigned short*)binp);
    int tid = threadIdx.x;
    for (int i = tid; i < 6 * 2 * 4 * 64; i += 256)
        ((uint4*)Bs)[i] = ((const uint4*)Bpk)[i];
    if (tid < 64) bs[tid] = binf[tid];
    __syncthreads();

    int w = tid >> 6, lane = tid & 63;
    int q = lane >> 4, n16 = lane & 15;
    int mrow = w * 16 + n16;
    int arow = min(blockIdx.x * 64 + mrow, N - 1);
    bf16x8 a0 = load_a8(A, f, (size_t)arow * 64 + 8 * q);
    bf16x8 a1 = load_a8(A, f, (size_t)arow * 64 + 8 * q + 32);

    float disv[4];
#pragma unroll
    for (int r = 0; r < 4; r++) {
        int node = blockIdx.x * 64 + w * 16 + 4 * q + r;
        disv[r] = dis[node];
    }

    size_t snode = (size_t)(blockIdx.x * 64 + mrow);

#pragma unroll
    for (int nt = 0; nt < 4; nt++) {
        f32x4 d = {0.f, 0.f, 0.f, 0.f};
        bf16x8 b0 = *(const bf16x8*)(Bs + (size_t)(((0 * 2 + 0) * 4 + nt) * 64 + lane) * 8);
        bf16x8 b1 = *(const bf16x8*)(Bs + (size_t)(((0 * 2 + 1) * 4 + nt) * 64 + lane) * 8);
        d = __builtin_amdgcn_mfma_f32_16x16x32_bf16(a0, b0, d, 0, 0, 0);
        d = __builtin_amdgcn_mfma_f32_16x16x32_bf16(a1, b1, d, 0, 0, 0);
        int col = nt * 16 + n16;
#pragma unroll
        for (int r = 0; r < 4; r++) {
            int rowl = w * 16 + 4 * q + r;
            float xval = d[r] + bs[col];
            Xs[rowl * 64 + col] = f2bf(xval);
            Xss[rowl * 64 + col] = f2bf(xval * disv[r]);
        }
    }
    // same-wave LDS RAW -> no barrier
    bf16x8 a20 = *(const bf16x8*)(Xs + mrow * 64 + 8 * q);
    bf16x8 a21 = *(const bf16x8*)(Xs + mrow * 64 + 8 * q + 32);

    for (int rel = 0; rel < REL; rel++) {
        int mat = 1 + rel;
#pragma unroll
        for (int nt = 0; nt < 4; nt++) {
            f32x4 d = {0.f, 0.f, 0.f, 0.f};
            bf16x8 b0 = *(const bf16x8*)(Bs + (size_t)(((mat * 2 + 0) * 4 + nt) * 64 + lane) * 8);
            bf16x8 b1 = *(const bf16x8*)(Bs + (size_t)(((mat * 2 + 1) * 4 + nt) * 64 + lane) * 8);
            d = __builtin_amdgcn_mfma_f32_16x16x32_bf16(a20, b0, d, 0, 0, 0);
            d = __builtin_amdgcn_mfma_f32_16x16x32_bf16(a21, b1, d, 0, 0, 0);
            int col = nt * 16 + n16;
#pragma unroll
            for (int r = 0; r < 4; r++)
                Ys[(w * 16 + 4 * q + r) * 64 + col] = f2bf(d[r]);
        }
        unsigned short* dst = Yi + ((size_t)rel * Np + snode) * 128;
#pragma unroll
        for (int ch = 0; ch < 2; ch++) {
            int c0 = 8 * q + 32 * ch;
            bf16x8 y8 = *(const bf16x8*)(Ys + mrow * 64 + c0);
            bf16x8 x8 = *(const bf16x8*)(Xss + mrow * 64 + c0);
            bf16x8 lo, hi;
#pragma unroll
            for (int j = 0; j < 4; j++) {
                lo[2 * j] = y8[j];     lo[2 * j + 1] = x8[j];
                hi[2 * j] = y8[4 + j]; hi[2 * j + 1] = x8[4 + j];
            }
            *(bf16x8*)(dst + 2 * c0)     = lo;
            *(bf16x8*)(dst + 2 * c0 + 8) = hi;
        }
    }
}

// ---------------------------------------------------------------------------
// K_main (fused with out-GEMM): block = 64 nodes, 4 waves x 16 nodes serial.
// Per node: 2 half-waves split edges, lane = 2 channels, 4x unroll.
// v rows staged in LDS (stride 72); same-wave MFMA epilogue -> out.
// ---------------------------------------------------------------------------
__global__ void __launch_bounds__(256)
k_main(const unsigned short* __restrict__ Yi, const int* __restrict__ off,
       const unsigned* __restrict__ edata4, const float* __restrict__ dis,
       const void* __restrict__ binp, const unsigned short* __restrict__ Bpk,
       const float* __restrict__ boutf, void* __restrict__ outv, int N, int Np) {
    __shared__ unsigned short Bs[2 * 4 * 64 * 8];   // 8 KB Wout frags
    __shared__ unsigned short Vs[64 * 72];          // 9 KB v rows (pad 72)
    __shared__ float Os[64 * 68];                   // 17 KB out staging (pad 68)
    __shared__ float bs[64];
    int f = det_f32((const unsigned short*)binp);
    int tid = threadIdx.x;
    const unsigned short* wsrc = Bpk + (size_t)6 * 2 * 4 * 64 * 8;
    for (int i = tid; i < 2 * 4 * 64; i += 256)
        ((uint4*)Bs)[i] = ((const uint4*)wsrc)[i];
    if (tid < 64) bs[tid] = boutf[tid];
    __syncthreads();

    int w = tid >> 6, lane = tid & 63;
    int half = lane >> 5;
    int co = (lane & 31) * 4;                 // ushort offset within 128-row
    int n0 = blockIdx.x * 64 + w * 16;

    for (int ln = 0; ln < 16; ln++) {
        int n = n0 + ln;
        float s0 = 0.f, s1 = 0.f, u0 = 0.f, u1 = 0.f, g0 = 0.f, g1 = 0.f;
        float s0b = 0.f, s1b = 0.f, u0b = 0.f, u1b = 0.f, g0b = 0.f, g1b = 0.f;
        if (n < N) {
            int e0 = off[n], e1 = off[n + 1];
            int e = e0 + half;
            for (; e + 6 < e1; e += 8) {
                unsigned md[4];
#pragma unroll
                for (int j = 0; j < 4; j++) md[j] = edata4[e + 2 * j];
                uint2 y[4];
#pragma unroll
                for (int j = 0; j < 4; j++) {
                    int c = md[j] & 0xFFFFF, t = md[j] >> 20;
                    y[j] = *(const uint2*)(Yi + ((size_t)t * Np + c) * 128 + co);
                }
#pragma unroll
                for (int j = 0; j < 4; j++) {
                    float r0 = __uint_as_float(y[j].x << 16);
                    float r1 = __uint_as_float(y[j].y << 16);
                    float p0 = __expf(fminf(r0, 60.f));
                    float p1 = __expf(fminf(r1, 60.f));
                    if (j & 1) {
                        g0b += __uint_as_float(y[j].x & 0xFFFF0000u);
                        g1b += __uint_as_float(y[j].y & 0xFFFF0000u);
                        s0b += p0; s1b += p1;
                        u0b += r0 * p0; u1b += r1 * p1;
                    } else {
                        g0 += __uint_as_float(y[j].x & 0xFFFF0000u);
                        g1 += __uint_as_float(y[j].y & 0xFFFF0000u);
                        s0 += p0; s1 += p1;
                        u0 += r0 * p0; u1 += r1 * p1;
                    }
                }
            }
            for (; e < e1; e += 2) {
                unsigned md = edata4[e];
                int c = md & 0xFFFFF, t = md >> 20;
                uint2 ya = *(const uint2*)(Yi + ((size_t)t * Np + c) * 128 + co);
                float r0 = __uint_as_float(ya.x << 16);
                float r1 = __uint_as_float(ya.y << 16);
                g0 += __uint_as_float(ya.x & 0xFFFF0000u);
                g1 += __uint_as_float(ya.y & 0xFFFF0000u);
                float p0 = __expf(fminf(r0, 60.f));
                float p1 = __expf(fminf(r1, 60.f));
                s0 += p0; s1 += p1;
                u0 += r0 * p0; u1 += r1 * p1;
            }
        }
        s0 += s0b; s1 += s1b; u0 += u0b; u1 += u1b; g0 += g0b; g1 += g1b;
        s0 += __shfl_xor(s0, 32); s1 += __shfl_xor(s1, 32);
        u0 += __shfl_xor(u0, 32); u1 += __shfl_xor(u1, 32);
        g0 += __shfl_xor(g0, 32); g1 += __shfl_xor(g1, 32);
        if (half == 0) {
            float dn = (n < N) ? dis[n] : 0.f;
            float m0 = u0 / (s0 + 1e-16f), m1 = u1 / (s1 + 1e-16f);
            float v0 = g0 * dn + 0.5f * fmaxf(m0, 0.f);
            float v1 = g1 * dn + 0.5f * fmaxf(m1, 0.f);
            unsigned pack = (unsigned)f2bf(v0) | ((unsigned)f2bf(v1) << 16);
            *(unsigned*)(Vs + (w * 16 + ln) * 72 + (lane & 31) * 2) = pack;
        }
    }

    // --- fused out-GEMM: wave w consumes only its own 16 Vs rows (no barrier)
    int q = lane >> 4, n16 = lane & 15;
    int mrow = w * 16 + n16;
    bf16x8 a0 = *(const bf16x8*)(Vs + mrow * 72 + 8 * q);
    bf16x8 a1 = *(const bf16x8*)(Vs + mrow * 72 + 8 * q + 32);
#pragma unroll
    for (int nt = 0; nt < 4; nt++) {
        f32x4 d = {0.f, 0.f, 0.f, 0.f};
        bf16x8 b0 = *(const bf16x8*)(Bs + (size_t)((0 * 4 + nt) * 64 + lane) * 8);
        bf16x8 b1 = *(const bf16x8*)(Bs + (size_t)((1 * 4 + nt) * 64 + lane) * 8);
        d = __builtin_amdgcn_mfma_f32_16x16x32_bf16(a0, b0, d, 0, 0, 0);
        d = __builtin_amdgcn_mfma_f32_16x16x32_bf16(a1, b1, d, 0, 0, 0);
        int col = nt * 16 + n16;
#pragma unroll
        for (int r = 0; r < 4; r++)
            Os[(w * 16 + 4 * q + r) * 68 + col] = d[r] + bs[col];
    }
    int node = blockIdx.x * 64 + mrow;
    if (node < N) {
        if (f) {
            float* dst = (float*)outv + (size_t)node * 64;
#pragma unroll
            for (int cchunk = 0; cchunk < 2; cchunk++) {
                int c0 = 8 * q + 32 * cchunk;
                *(f32x4*)(dst + c0)     = *(const f32x4*)(Os + mrow * 68 + c0);
                *(f32x4*)(dst + c0 + 4) = *(const f32x4*)(Os + mrow * 68 + c0 + 4);
            }
        } else {
            unsigned short* dst = (unsigned short*)outv + (size_t)node * 64;
#pragma unroll
            for (int cchunk = 0; cchunk < 2; cchunk++) {
                int c0 = 8 * q + 32 * cchunk;
                bf16x8 pk;
#pragma unroll
                for (int j = 0; j < 8; j++)
                    pk[j] = (short)f2bf(Os[mrow * 68 + c0 + j]);
                *(bf16x8*)(dst + c0) = pk;
            }
        }
    }
}

// ---------------------------------------------------------------------------
extern "C" void kernel_launch(void* const* d_in, const int* in_sizes, int n_in,
                              void* d_out, int out_size, void* d_ws, size_t ws_size,
                              hipStream_t stream) {
    const void* A    = d_in[0];
    const void* Win  = d_in[2];
    const void* bin  = d_in[3];
    const void* Wrel = d_in[4];
    const void* Wout = d_in[5];
    const void* bout = d_in[6];
    const int* ei = (const int*)d_in[7];
    const int* et = (const int*)d_in[8];
    int N = in_sizes[0] / HID;          // 50000
    int E = in_sizes[8];                // 800000
    int Np = ((N + BKT - 1) / BKT) * BKT;  // 50176
    int NB = Np / BKT;                  // 196
    int nblk = (E + EPB - 1) / EPB;     // 196
    int M = 2 * NB * nblk;
    int nsb = (M + 1023) / 1024;

    char* p = (char*)d_ws;
    auto carve = [&](size_t bytes) {
        char* q = p;
        p += (bytes + 15) & ~(size_t)15;
        return q;
    };
    unsigned short* Yi   = (unsigned short*)carve((size_t)REL * Np * 128 * 2); // 64.2 MB
    unsigned*       rbuf = (unsigned*)carve((size_t)E * 4);                    // 3.2 MB
    unsigned char*  cb8  = (unsigned char*)carve((size_t)E);                   // 0.8 MB
    unsigned*       edata4 = (unsigned*)carve((size_t)E * 4);                  // 3.2 MB
    int*            hist = (int*)carve((size_t)M * 4);                         // 0.3 MB
    unsigned short* Bpk  = (unsigned short*)carve((size_t)7 * 4096 * 2);
    float* binf  = (float*)carve(64 * 4);
    float* boutf = (float*)carve(64 * 4);
    int* off     = (int*)carve((size_t)(N + 1) * 4);
    float* dis   = (float*)carve((size_t)Np * 4);
    int* bsum    = (int*)carve((size_t)nsb * 4);

    size_t lds_part = (size_t)2 * NB * 4;  // 1.6 KB dynamic LDS

    k_pack<<<14, 256, 0, stream>>>(Win, bin, Wrel, Wout, bout, Bpk, binf, boutf);
    k_p1a<<<nblk, 256, lds_part, stream>>>(ei, hist, E, NB, nblk);
    s_blk<<<nsb, 256, 0, stream>>>(hist, bsum, M);
    s_apply<<<nsb, 256, 0, stream>>>(hist, bsum, M, nsb);
    k_p1c<<<nblk, 256, lds_part, stream>>>(ei, et, hist, rbuf, cb8, E, NB, nblk);
    k_p2<<<2 * NB, 256, 0, stream>>>(rbuf, cb8, hist, off, edata4, dis, E, N, NB, nblk);
    k_xy<<<Np / 64, 256, 0, stream>>>(A, bin, Bpk, binf, dis, Yi, N, Np);
    k_main<<<Np / 64, 256, 0, stream>>>(Yi, off, edata4, dis, bin, Bpk, boutf,
                                        d_out, N, Np);
}

// Round 12
// 189.610 us; speedup vs baseline: 1.1524x; 1.1524x over previous
//
#include <hip/hip_runtime.h>
#include <hip/hip_bf16.h>

#define HID 64
#define REL 5
#define EPB 4096          // edges per partition block (16/thread * 256)
#define BKT 256           // nodes per sort bucket

typedef short bf16x8 __attribute__((ext_vector_type(8)));
typedef float f32x4 __attribute__((ext_vector_type(4)));

__device__ __forceinline__ float bf2f(unsigned short u) {
    return __uint_as_float(((unsigned)u) << 16);
}
__device__ __forceinline__ unsigned short f2bf(float f) {
    __hip_bfloat16 h = (__hip_bfloat16)f;   // RNE
    return *(unsigned short*)&h;
}
// Per-wave inline dtype detection (no separate kernel, no flags buffer).
__device__ __forceinline__ int det_f32(const unsigned short* __restrict__ wb) {
    int lane = threadIdx.x & 63;
    bool big = (lane < 32) ? (fabsf(bf2f(wb[2 * lane])) > 0.26f) : false;
    return (__ballot(big) != 0ull) ? 1 : 0;
}
__device__ __forceinline__ int det_i64(const int* __restrict__ ei) {
    int lane = threadIdx.x & 63;
    bool odd_nz = (ei[2 * lane + 1] != 0);
    return (__ballot(odd_nz) == 0ull) ? 1 : 0;
}
__device__ __forceinline__ void dec_edge(const int* __restrict__ ei, int i64,
                                         int E, int e, int& r, int& c) {
    if (i64) { r = ei[2 * e]; c = ei[2 * (E + e)]; }
    else     { r = ei[e];     c = ei[E + e]; }
}

// ---------------------------------------------------------------------------
// K_p1a + pack fused: blocks [0,nblk) build per-block LDS histograms of
// r/BKT and c/BKT; blocks [nblk, nblk+14) repack weights into MFMA B-fragment
// order (Bpk[mat][ks][nt][lane][j]; mat: 0=Win, 1..5=Wrel, 6=Wout).
// ---------------------------------------------------------------------------
__global__ void k_p1a_pack(const int* __restrict__ ei, int* __restrict__ hist,
                           int E, int NB, int nblk,
                           const void* Win, const void* bin, const void* Wr,
                           const void* Wout, const void* bout,
                           unsigned short* __restrict__ Bpk,
                           float* __restrict__ binf, float* __restrict__ boutf) {
    if (blockIdx.x >= (unsigned)nblk) {
        // ---- pack work ----
        int f = det_f32((const unsigned short*)bin);
        int gid = (blockIdx.x - nblk) * 256 + threadIdx.x;
        if (gid < 7 * 2 * 4 * 64) {
            int lane = gid & 63;
            int nt = (gid >> 6) & 3;
            int ks = (gid >> 8) & 1;
            int mat = gid >> 9;
            int q = lane >> 4, n = nt * 16 + (lane & 15);
#pragma unroll
            for (int j = 0; j < 8; j++) {
                int k = ks * 32 + q * 8 + j;
                int idx = k * 64 + n;
                float val;
                if (mat == 0)
                    val = f ? ((const float*)Win)[idx] : bf2f(((const unsigned short*)Win)[idx]);
                else if (mat <= 5) {
                    int ii = (mat - 1) * 4096 + idx;
                    val = f ? ((const float*)Wr)[ii] : bf2f(((const unsigned short*)Wr)[ii]);
                } else
                    val = f ? ((const float*)Wout)[idx] : bf2f(((const unsigned short*)Wout)[idx]);
                Bpk[(size_t)gid * 8 + j] = f2bf(val);
            }
        }
        if (gid < 64)
            binf[gid] = f ? ((const float*)bin)[gid] : bf2f(((const unsigned short*)bin)[gid]);
        else if (gid >= 64 && gid < 128) {
            int i = gid - 64;
            boutf[i] = f ? ((const float*)bout)[i] : bf2f(((const unsigned short*)bout)[i]);
        }
        return;
    }
    // ---- p1a work ----
    extern __shared__ int lh[];  // 2*NB
    int i64 = det_i64(ei);
    int tid = threadIdx.x, blk = blockIdx.x;
    for (int i = tid; i < 2 * NB; i += 256) lh[i] = 0;
    __syncthreads();
#pragma unroll
    for (int k = 0; k < EPB / 256; k++) {
        int e = blk * EPB + k * 256 + tid;
        if (e < E) {
            int r, c;
            dec_edge(ei, i64, E, e, r, c);
            atomicAdd(&lh[r >> 8], 1);
            atomicAdd(&lh[NB + (c >> 8)], 1);
        }
    }
    __syncthreads();
    int NBn = NB * nblk;
    for (int i = tid; i < NB; i += 256) {
        hist[i * nblk + blk] = lh[i];
        hist[NBn + i * nblk + blk] = lh[NB + i];
    }
}

// ---------------------------------------------------------------------------
// Scan (2 kernels)
// ---------------------------------------------------------------------------
__global__ void s_blk(const int* __restrict__ v, int* __restrict__ bsum, int M) {
    __shared__ int red[256];
    int t = threadIdx.x;
    int i0 = blockIdx.x * 1024 + t * 4;
    int s = 0;
#pragma unroll
    for (int j = 0; j < 4; j++) { int i = i0 + j; if (i < M) s += v[i]; }
    red[t] = s;
    __syncthreads();
    for (int d = 128; d > 0; d >>= 1) {
        if (t < d) red[t] += red[t + d];
        __syncthreads();
    }
    if (t == 0) bsum[blockIdx.x] = red[0];
}

__global__ void s_apply(int* __restrict__ v, const int* __restrict__ bsum,
                        int M, int nsb) {
    __shared__ int red[256];
    int t = threadIdx.x, bk = blockIdx.x;
    int acc = 0;
    for (int i = t; i < nsb; i += 256)
        if (i < bk) acc += bsum[i];
    red[t] = acc;
    __syncthreads();
    for (int d = 128; d > 0; d >>= 1) {
        if (t < d) red[t] += red[t + d];
        __syncthreads();
    }
    int base = red[0];
    __syncthreads();
    int i0 = bk * 1024 + t * 4;
    int x[4];
    int s = 0;
#pragma unroll
    for (int j = 0; j < 4; j++) {
        int i = i0 + j;
        x[j] = (i < M) ? v[i] : 0;
        s += x[j];
    }
    red[t] = s;
    __syncthreads();
    for (int d = 1; d < 256; d <<= 1) {
        int add = (t >= d) ? red[t - d] : 0;
        __syncthreads();
        red[t] += add;
        __syncthreads();
    }
    int run = base + red[t] - s;
#pragma unroll
    for (int j = 0; j < 4; j++) {
        int i = i0 + j;
        if (i < M) { int tmp = x[j]; v[i] = run; run += tmp; }
    }
}

// ---------------------------------------------------------------------------
// P1c: partition. rbuf[posR] = (r&255)<<20 | t<<17 | c ; cb8[posC] = c&255.
// ---------------------------------------------------------------------------
__global__ void k_p1c(const int* __restrict__ ei, const int* __restrict__ et,
                      const int* __restrict__ hist,
                      unsigned* __restrict__ rbuf, unsigned char* __restrict__ cb8,
                      int E, int NB, int nblk) {
    extern __shared__ int lh[];  // 2*NB rank counters
    int i64 = det_i64(ei);
    int tid = threadIdx.x, blk = blockIdx.x;
    for (int i = tid; i < 2 * NB; i += 256) lh[i] = 0;
    __syncthreads();
    int NBn = NB * nblk;
#pragma unroll
    for (int k = 0; k < EPB / 256; k++) {
        int e = blk * EPB + k * 256 + tid;
        if (e < E) {
            int r, c;
            dec_edge(ei, i64, E, e, r, c);
            int t = et[e];
            int binR = r >> 8;
            int posR = hist[binR * nblk + blk] + atomicAdd(&lh[binR], 1);
            rbuf[posR] = ((unsigned)(r & 255) << 20) | ((unsigned)t << 17) | (unsigned)c;
            int binC = c >> 8;
            int posC = hist[NBn + binC * nblk + blk] - E + atomicAdd(&lh[NB + binC], 1);
            cb8[posC] = (unsigned char)(c & 255);
        }
    }
}

// ---------------------------------------------------------------------------
// P2 (merged): blocks [0,NB) = r-side (off[] + final edata4);
//              blocks [NB,2NB) = c-side (dis[]).
// ---------------------------------------------------------------------------
__global__ void k_p2(const unsigned* __restrict__ rbuf, const unsigned char* __restrict__ cb8,
                     const int* __restrict__ hist,
                     int* __restrict__ off, unsigned* __restrict__ edata4,
                     float* __restrict__ dis, int E, int N, int NB, int nblk) {
    __shared__ int lcnt[BKT], excl[BKT], lcnt2[BKT];
    int tid = threadIdx.x;
    int bk = blockIdx.x;
    if (bk < NB) {
        int bstart = hist[bk * nblk];
        int bend = (bk + 1 < NB) ? hist[(bk + 1) * nblk] : E;
        lcnt[tid] = 0; lcnt2[tid] = 0;
        __syncthreads();
        for (int e = bstart + tid; e < bend; e += 256)
            atomicAdd(&lcnt[(rbuf[e] >> 20) & 255], 1);
        __syncthreads();
        int s = lcnt[tid];
        excl[tid] = s;
        __syncthreads();
        for (int d = 1; d < 256; d <<= 1) {
            int add = (tid >= d) ? excl[tid - d] : 0;
            __syncthreads();
            excl[tid] += add;
            __syncthreads();
        }
        int base = excl[tid] - s;
        excl[tid] = base;
        __syncthreads();
        int node = bk * BKT + tid;
        if (node < N) off[node] = bstart + base;
        if (bk == 0 && tid == 0) off[N] = E;
        for (int e = bstart + tid; e < bend; e += 256) {
            unsigned rec = rbuf[e];
            int rl = (rec >> 20) & 255;
            int t = (rec >> 17) & 7;
            int c = rec & 0x1FFFF;
            int pos = bstart + excl[rl] + atomicAdd(&lcnt2[rl], 1);
            edata4[pos] = (unsigned)c | ((unsigned)t << 20);
        }
    } else {
        int bk2 = bk - NB;
        int NBn = NB * nblk;
        int cstart = hist[NBn + bk2 * nblk] - E;
        int cend = (bk2 + 1 < NB) ? hist[NBn + (bk2 + 1) * nblk] - E : E;
        lcnt[tid] = 0;
        __syncthreads();
        for (int e = cstart + tid; e < cend; e += 256)
            atomicAdd(&lcnt[cb8[e]], 1);
        __syncthreads();
        int node = bk2 * BKT + tid;   // covers all Np
        int d = lcnt[tid];
        dis[node] = (d > 0) ? rsqrtf((float)d) : 0.f;   // padding nodes -> 0
    }
}

// ---------------------------------------------------------------------------
// K_xy (MFMA): x = A@Win + b ; Y[r] = bf16(x)@Wrel[r].
// Yi layout [5][Np] rows of 128 ushorts: 2*ch = y[ch], 2*ch+1 = (x*dis)[ch].
// ---------------------------------------------------------------------------
__device__ __forceinline__ bf16x8 load_a8(const void* A, int f, size_t base) {
    if (f) {
        const float* Af = (const float*)A + base;
        bf16x8 r;
#pragma unroll
        for (int j = 0; j < 8; j++) r[j] = (short)f2bf(Af[j]);
        return r;
    }
    return *(const bf16x8*)((const unsigned short*)A + base);
}

__global__ void __launch_bounds__(256)
k_xy(const void* __restrict__ A, const void* __restrict__ binp,
     const unsigned short* __restrict__ Bpk,
     const float* __restrict__ binf, const float* __restrict__ dis,
     unsigned short* __restrict__ Yi, int N, int Np) {
    __shared__ unsigned short Bs[6 * 2 * 4 * 64 * 8];  // 48 KB
    __shared__ unsigned short Xs[64 * 64];             // 8 KB  x (frag source)
    __shared__ unsigned short Xss[64 * 64];            // 8 KB  x*dis
    __shared__ unsigned short Ys[64 * 64];             // 8 KB  y staging
    __shared__ float bs[64];
    int f = det_f32((const unsigned short*)binp);
    int tid = threadIdx.x;
    for (int i = tid; i < 6 * 2 * 4 * 64; i += 256)
        ((uint4*)Bs)[i] = ((const uint4*)Bpk)[i];
    if (tid < 64) bs[tid] = binf[tid];
    __syncthreads();

    int w = tid >> 6, lane = tid & 63;
    int q = lane >> 4, n16 = lane & 15;
    int mrow = w * 16 + n16;
    int arow = min(blockIdx.x * 64 + mrow, N - 1);
    bf16x8 a0 = load_a8(A, f, (size_t)arow * 64 + 8 * q);
    bf16x8 a1 = load_a8(A, f, (size_t)arow * 64 + 8 * q + 32);

    float disv[4];
#pragma unroll
    for (int r = 0; r < 4; r++) {
        int node = blockIdx.x * 64 + w * 16 + 4 * q + r;
        disv[r] = dis[node];
    }

    size_t snode = (size_t)(blockIdx.x * 64 + mrow);

#pragma unroll
    for (int nt = 0; nt < 4; nt++) {
        f32x4 d = {0.f, 0.f, 0.f, 0.f};
        bf16x8 b0 = *(const bf16x8*)(Bs + (size_t)(((0 * 2 + 0) * 4 + nt) * 64 + lane) * 8);
        bf16x8 b1 = *(const bf16x8*)(Bs + (size_t)(((0 * 2 + 1) * 4 + nt) * 64 + lane) * 8);
        d = __builtin_amdgcn_mfma_f32_16x16x32_bf16(a0, b0, d, 0, 0, 0);
        d = __builtin_amdgcn_mfma_f32_16x16x32_bf16(a1, b1, d, 0, 0, 0);
        int col = nt * 16 + n16;
#pragma unroll
        for (int r = 0; r < 4; r++) {
            int rowl = w * 16 + 4 * q + r;
            float xval = d[r] + bs[col];
            Xs[rowl * 64 + col] = f2bf(xval);
            Xss[rowl * 64 + col] = f2bf(xval * disv[r]);
        }
    }
    // same-wave LDS RAW -> no barrier
    bf16x8 a20 = *(const bf16x8*)(Xs + mrow * 64 + 8 * q);
    bf16x8 a21 = *(const bf16x8*)(Xs + mrow * 64 + 8 * q + 32);

    for (int rel = 0; rel < REL; rel++) {
        int mat = 1 + rel;
#pragma unroll
        for (int nt = 0; nt < 4; nt++) {
            f32x4 d = {0.f, 0.f, 0.f, 0.f};
            bf16x8 b0 = *(const bf16x8*)(Bs + (size_t)(((mat * 2 + 0) * 4 + nt) * 64 + lane) * 8);
            bf16x8 b1 = *(const bf16x8*)(Bs + (size_t)(((mat * 2 + 1) * 4 + nt) * 64 + lane) * 8);
            d = __builtin_amdgcn_mfma_f32_16x16x32_bf16(a20, b0, d, 0, 0, 0);
            d = __builtin_amdgcn_mfma_f32_16x16x32_bf16(a21, b1, d, 0, 0, 0);
            int col = nt * 16 + n16;
#pragma unroll
            for (int r = 0; r < 4; r++)
                Ys[(w * 16 + 4 * q + r) * 64 + col] = f2bf(d[r]);
        }
        unsigned short* dst = Yi + ((size_t)rel * Np + snode) * 128;
#pragma unroll
        for (int ch = 0; ch < 2; ch++) {
            int c0 = 8 * q + 32 * ch;
            bf16x8 y8 = *(const bf16x8*)(Ys + mrow * 64 + c0);
            bf16x8 x8 = *(const bf16x8*)(Xss + mrow * 64 + c0);
            bf16x8 lo, hi;
#pragma unroll
            for (int j = 0; j < 4; j++) {
                lo[2 * j] = y8[j];     lo[2 * j + 1] = x8[j];
                hi[2 * j] = y8[4 + j]; hi[2 * j + 1] = x8[4 + j];
            }
            *(bf16x8*)(dst + 2 * c0)     = lo;
            *(bf16x8*)(dst + 2 * c0 + 8) = hi;
        }
    }
}

// ---------------------------------------------------------------------------
// K_main: one node per wave (max TLP); 2 half-waves split edges; lane = 2 ch.
// 4x unroll per half (8 outstanding row-gathers). One uint2 per edge per lane.
// ---------------------------------------------------------------------------
__global__ void __launch_bounds__(256)
k_main(const unsigned short* __restrict__ Yi, const int* __restrict__ off,
       const unsigned* __restrict__ edata4, const float* __restrict__ dis,
       unsigned short* __restrict__ v, int N, int Np) {
    int tid = threadIdx.x;
    int wv = tid >> 6, lane = tid & 63;
    int n = blockIdx.x * 4 + wv;
    if (n >= N) return;
    int half = lane >> 5;
    int co = (lane & 31) * 4;                 // ushort offset within 128-row
    int e0 = off[n], e1 = off[n + 1];
    float s0 = 0.f, s1 = 0.f, u0 = 0.f, u1 = 0.f, g0 = 0.f, g1 = 0.f;
    float s0b = 0.f, s1b = 0.f, u0b = 0.f, u1b = 0.f, g0b = 0.f, g1b = 0.f;

    int e = e0 + half;
    for (; e + 6 < e1; e += 8) {
        unsigned md[4];
#pragma unroll
        for (int j = 0; j < 4; j++) md[j] = edata4[e + 2 * j];
        uint2 y[4];
#pragma unroll
        for (int j = 0; j < 4; j++) {
            int c = md[j] & 0xFFFFF, t = md[j] >> 20;
            y[j] = *(const uint2*)(Yi + ((size_t)t * Np + c) * 128 + co);
        }
#pragma unroll
        for (int j = 0; j < 4; j++) {
            float r0 = __uint_as_float(y[j].x << 16);
            float r1 = __uint_as_float(y[j].y << 16);
            float p0 = __expf(fminf(r0, 60.f));
            float p1 = __expf(fminf(r1, 60.f));
            if (j & 1) {
                g0b += __uint_as_float(y[j].x & 0xFFFF0000u);
                g1b += __uint_as_float(y[j].y & 0xFFFF0000u);
                s0b += p0; s1b += p1;
                u0b += r0 * p0; u1b += r1 * p1;
            } else {
                g0 += __uint_as_float(y[j].x & 0xFFFF0000u);
                g1 += __uint_as_float(y[j].y & 0xFFFF0000u);
                s0 += p0; s1 += p1;
                u0 += r0 * p0; u1 += r1 * p1;
            }
        }
    }
    for (; e < e1; e += 2) {
        unsigned md = edata4[e];
        int c = md & 0xFFFFF, t = md >> 20;
        uint2 ya = *(const uint2*)(Yi + ((size_t)t * Np + c) * 128 + co);
        float r0 = __uint_as_float(ya.x << 16);
        float r1 = __uint_as_float(ya.y << 16);
        g0 += __uint_as_float(ya.x & 0xFFFF0000u);
        g1 += __uint_as_float(ya.y & 0xFFFF0000u);
        float p0 = __expf(fminf(r0, 60.f));
        float p1 = __expf(fminf(r1, 60.f));
        s0 += p0; s1 += p1;
        u0 += r0 * p0; u1 += r1 * p1;
    }
    s0 += s0b; s1 += s1b; u0 += u0b; u1 += u1b; g0 += g0b; g1 += g1b;

    s0 += __shfl_xor(s0, 32); s1 += __shfl_xor(s1, 32);
    u0 += __shfl_xor(u0, 32); u1 += __shfl_xor(u1, 32);
    g0 += __shfl_xor(g0, 32); g1 += __shfl_xor(g1, 32);
    if (half == 0) {
        float dn = dis[n];
        float m0 = u0 / (s0 + 1e-16f), m1 = u1 / (s1 + 1e-16f);
        float v0 = g0 * dn + 0.5f * fmaxf(m0, 0.f);
        float v1 = g1 * dn + 0.5f * fmaxf(m1, 0.f);
        unsigned pack = (unsigned)f2bf(v0) | ((unsigned)f2bf(v1) << 16);
        *(unsigned*)(v + (size_t)n * 64 + (lane & 31) * 2) = pack;
    }
}

// ---------------------------------------------------------------------------
// K_out (MFMA): out = v @ Wout + bout. LDS-transposed vector stores.
// ---------------------------------------------------------------------------
__global__ void __launch_bounds__(256)
k_out(const unsigned short* __restrict__ v, const void* __restrict__ binp,
      const unsigned short* __restrict__ Bpk,
      const float* __restrict__ boutf, void* __restrict__ outv, int N, int Np) {
    __shared__ unsigned short Bs[2 * 4 * 64 * 8];  // 8 KB (mat 6)
    __shared__ float Os[64 * 64];                  // 16 KB staging
    __shared__ float bs[64];
    int f = det_f32((const unsigned short*)binp);
    int tid = threadIdx.x;
    const unsigned short* src = Bpk + (size_t)6 * 2 * 4 * 64 * 8;
    for (int i = tid; i < 2 * 4 * 64; i += 256)
        ((uint4*)Bs)[i] = ((const uint4*)src)[i];
    if (tid < 64) bs[tid] = boutf[tid];
    __syncthreads();

    int w = tid >> 6, lane = tid & 63;
    int q = lane >> 4, n16 = lane & 15;
    int mrow = w * 16 + n16;
    int arow = min(blockIdx.x * 64 + mrow, N - 1);
    bf16x8 a0 = *(const bf16x8*)(v + (size_t)arow * 64 + 8 * q);
    bf16x8 a1 = *(const bf16x8*)(v + (size_t)arow * 64 + 8 * q + 32);
#pragma unroll
    for (int nt = 0; nt < 4; nt++) {
        f32x4 d = {0.f, 0.f, 0.f, 0.f};
        bf16x8 b0 = *(const bf16x8*)(Bs + (size_t)((0 * 4 + nt) * 64 + lane) * 8);
        bf16x8 b1 = *(const bf16x8*)(Bs + (size_t)((1 * 4 + nt) * 64 + lane) * 8);
        d = __builtin_amdgcn_mfma_f32_16x16x32_bf16(a0, b0, d, 0, 0, 0);
        d = __builtin_amdgcn_mfma_f32_16x16x32_bf16(a1, b1, d, 0, 0, 0);
        int col = nt * 16 + n16;
#pragma unroll
        for (int r = 0; r < 4; r++)
            Os[(w * 16 + 4 * q + r) * 64 + col] = d[r] + bs[col];
    }
    int node = blockIdx.x * 64 + mrow;
    if (node < N) {
        if (f) {
            float* dst = (float*)outv + (size_t)node * 64;
#pragma unroll
            for (int cchunk = 0; cchunk < 2; cchunk++) {
                int c0 = 8 * q + 32 * cchunk;
                *(f32x4*)(dst + c0)     = *(const f32x4*)(Os + mrow * 64 + c0);
                *(f32x4*)(dst + c0 + 4) = *(const f32x4*)(Os + mrow * 64 + c0 + 4);
            }
        } else {
            unsigned short* dst = (unsigned short*)outv + (size_t)node * 64;
#pragma unroll
            for (int cchunk = 0; cchunk < 2; cchunk++) {
                int c0 = 8 * q + 32 * cchunk;
                bf16x8 pk;
#pragma unroll
                for (int j = 0; j < 8; j++)
                    pk[j] = (short)f2bf(Os[mrow * 64 + c0 + j]);
                *(bf16x8*)(dst + c0) = pk;
            }
        }
    }
}

// ---------------------------------------------------------------------------
extern "C" void kernel_launch(void* const* d_in, const int* in_sizes, int n_in,
                              void* d_out, int out_size, void* d_ws, size_t ws_size,
                              hipStream_t stream) {
    const void* A    = d_in[0];
    const void* Win  = d_in[2];
    const void* bin  = d_in[3];
    const void* Wrel = d_in[4];
    const void* Wout = d_in[5];
    const void* bout = d_in[6];
    const int* ei = (const int*)d_in[7];
    const int* et = (const int*)d_in[8];
    int N = in_sizes[0] / HID;          // 50000
    int E = in_sizes[8];                // 800000
    int Np = ((N + BKT - 1) / BKT) * BKT;  // 50176
    int NB = Np / BKT;                  // 196
    int nblk = (E + EPB - 1) / EPB;     // 196
    int M = 2 * NB * nblk;
    int nsb = (M + 1023) / 1024;

    char* p = (char*)d_ws;
    auto carve = [&](size_t bytes) {
        char* q = p;
        p += (bytes + 15) & ~(size_t)15;
        return q;
    };
    unsigned short* Yi   = (unsigned short*)carve((size_t)REL * Np * 128 * 2); // 64.2 MB
    unsigned short* vv   = (unsigned short*)carve((size_t)Np * 64 * 2);        // 6.4 MB
    unsigned*       rbuf = (unsigned*)carve((size_t)E * 4);                    // 3.2 MB
    unsigned char*  cb8  = (unsigned char*)carve((size_t)E);                   // 0.8 MB
    unsigned*       edata4 = (unsigned*)carve((size_t)E * 4);                  // 3.2 MB
    int*            hist = (int*)carve((size_t)M * 4);                         // 0.3 MB
    unsigned short* Bpk  = (unsigned short*)carve((size_t)7 * 4096 * 2);
    float* binf  = (float*)carve(64 * 4);
    float* boutf = (float*)carve(64 * 4);
    int* off     = (int*)carve((size_t)(N + 1) * 4);
    float* dis   = (float*)carve((size_t)Np * 4);
    int* bsum    = (int*)carve((size_t)nsb * 4);

    size_t lds_part = (size_t)2 * NB * 4;  // 1.6 KB dynamic LDS

    k_p1a_pack<<<nblk + 14, 256, lds_part, stream>>>(ei, hist, E, NB, nblk,
                                                     Win, bin, Wrel, Wout, bout,
                                                     Bpk, binf, boutf);
    s_blk<<<nsb, 256, 0, stream>>>(hist, bsum, M);
    s_apply<<<nsb, 256, 0, stream>>>(hist, bsum, M, nsb);
    k_p1c<<<nblk, 256, lds_part, stream>>>(ei, et, hist, rbuf, cb8, E, NB, nblk);
    k_p2<<<2 * NB, 256, 0, stream>>>(rbuf, cb8, hist, off, edata4, dis, E, N, NB, nblk);
    k_xy<<<Np / 64, 256, 0, stream>>>(A, bin, Bpk, binf, dis, Yi, N, Np);
    k_main<<<(N + 3) / 4, 256, 0, stream>>>(Yi, off, edata4, dis, vv, N, Np);
    k_out<<<Np / 64, 256, 0, stream>>>(vv, bin, Bpk, boutf, d_out, N, Np);
}